// Round 1
// baseline (3996.776 us; speedup 1.0000x reference)
//
#include <hip/hip_runtime.h>
#include <hip/hip_bf16.h>

// ---------------------------------------------------------------------------
// Problem constants (reference: N=16384, F=H1=H2=128, G=64)
// ---------------------------------------------------------------------------
#define NN 16384
#define GG 64
#define BN_EPS 1e-5f

// ---------------------------------------------------------------------------
// Big GEMM: C[N x 128] += A[rowblock, k-half] @ B[k-half, 0:128]   (fp32)
// A: N x N row-major, B: N x 128 row-major. grid = (N/64, 2 k-splits).
// Tile 64x128, block 256, micro 8x4, BK=32. Epilogue: atomicAdd (C pre-zeroed).
// ---------------------------------------------------------------------------
__global__ __launch_bounds__(256) void gemm_big(const float* __restrict__ A,
                                                const float* __restrict__ B,
                                                float* __restrict__ C, int N) {
  __shared__ float As[32][68];   // transposed A tile, +4 pad keeps 16B align & breaks bank stride
  __shared__ float Bs[32][128];
  const int tid = threadIdx.x;
  const int row0 = blockIdx.x * 64;
  const long k0 = (long)blockIdx.y * (N / 2);
  const int tr = tid >> 5;       // 0..7 -> rows tr*8..+7
  const int tc = tid & 31;       // 0..31 -> cols tc*4..+3
  float acc[8][4] = {};

  for (int kc = 0; kc < N / 2; kc += 32) {
    const long kb = k0 + kc;
    // stage A tile 64x32 (2 float4 / thread), store transposed As[k][row]
#pragma unroll
    for (int i = 0; i < 2; ++i) {
      int e = i * 256 + tid;
      int ar = e >> 3, ak = (e & 7) * 4;
      float4 v = *(const float4*)&A[(long)(row0 + ar) * N + kb + ak];
      As[ak + 0][ar] = v.x; As[ak + 1][ar] = v.y;
      As[ak + 2][ar] = v.z; As[ak + 3][ar] = v.w;
    }
    // stage B tile 32x128 (4 float4 / thread)
#pragma unroll
    for (int i = 0; i < 4; ++i) {
      int e = i * 256 + tid;
      int br = e >> 5, bc = (e & 31) * 4;
      *(float4*)&Bs[br][bc] = *(const float4*)&B[(kb + br) * 128 + bc];
    }
    __syncthreads();
#pragma unroll
    for (int k = 0; k < 32; ++k) {
      float4 a0 = *(const float4*)&As[k][tr * 8];
      float4 a1 = *(const float4*)&As[k][tr * 8 + 4];
      float4 b  = *(const float4*)&Bs[k][tc * 4];
      float am[8] = {a0.x, a0.y, a0.z, a0.w, a1.x, a1.y, a1.z, a1.w};
      float bm[4] = {b.x, b.y, b.z, b.w};
#pragma unroll
      for (int i = 0; i < 8; ++i)
#pragma unroll
        for (int j = 0; j < 4; ++j) acc[i][j] += am[i] * bm[j];
    }
    __syncthreads();
  }
#pragma unroll
  for (int i = 0; i < 8; ++i)
#pragma unroll
    for (int j = 0; j < 4; ++j)
      atomicAdd(&C[(long)(row0 + tr * 8 + i) * 128 + (tc * 4 + j)], acc[i][j]);
}

// ---------------------------------------------------------------------------
// FC: Y = relu([X0 | X1] @ W + bias), X0/X1: N x 128, W: 256 x 128 row-major.
// Tile 64x128, block 256, micro 8x4, K=256 (two 128-phases).
// ---------------------------------------------------------------------------
__global__ __launch_bounds__(256) void fc_relu(const float* __restrict__ X0,
                                               const float* __restrict__ X1,
                                               const float* __restrict__ W,
                                               const float* __restrict__ bias,
                                               float* __restrict__ Y, int N) {
  __shared__ float As[32][68];
  __shared__ float Bs[32][128];
  const int tid = threadIdx.x;
  const int row0 = blockIdx.x * 64;
  const int tr = tid >> 5, tc = tid & 31;
  float acc[8][4] = {};

  for (int p = 0; p < 2; ++p) {
    const float* __restrict__ X = p ? X1 : X0;
    for (int kc = 0; kc < 128; kc += 32) {
#pragma unroll
      for (int i = 0; i < 2; ++i) {
        int e = i * 256 + tid;
        int ar = e >> 3, ak = (e & 7) * 4;
        float4 v = *(const float4*)&X[(long)(row0 + ar) * 128 + kc + ak];
        As[ak + 0][ar] = v.x; As[ak + 1][ar] = v.y;
        As[ak + 2][ar] = v.z; As[ak + 3][ar] = v.w;
      }
#pragma unroll
      for (int i = 0; i < 4; ++i) {
        int e = i * 256 + tid;
        int br = e >> 5, bc = (e & 31) * 4;
        *(float4*)&Bs[br][bc] = *(const float4*)&W[(p * 128 + kc + br) * 128 + bc];
      }
      __syncthreads();
#pragma unroll
      for (int k = 0; k < 32; ++k) {
        float4 a0 = *(const float4*)&As[k][tr * 8];
        float4 a1 = *(const float4*)&As[k][tr * 8 + 4];
        float4 b  = *(const float4*)&Bs[k][tc * 4];
        float am[8] = {a0.x, a0.y, a0.z, a0.w, a1.x, a1.y, a1.z, a1.w};
        float bm[4] = {b.x, b.y, b.z, b.w};
#pragma unroll
        for (int i = 0; i < 8; ++i)
#pragma unroll
          for (int j = 0; j < 4; ++j) acc[i][j] += am[i] * bm[j];
      }
      __syncthreads();
    }
  }
#pragma unroll
  for (int i = 0; i < 8; ++i)
#pragma unroll
    for (int j = 0; j < 4; ++j) {
      int r = row0 + tr * 8 + i, c = tc * 4 + j;
      float v = acc[i][j] + bias[c];
      Y[(long)r * 128 + c] = v > 0.f ? v : 0.f;
    }
}

// ---------------------------------------------------------------------------
// Column sums / sumsq of Y (N x 128) for batchnorm stats. grid=64, 256 rows each.
// ---------------------------------------------------------------------------
__global__ __launch_bounds__(256) void col_stats(const float* __restrict__ Y,
                                                 float* __restrict__ sum,
                                                 float* __restrict__ sumsq) {
  const int tid = threadIdx.x;
  const int col = tid & 127, sub = tid >> 7;
  const long r0 = (long)blockIdx.x * 256 + sub * 128;
  float s = 0.f, q = 0.f;
  for (int r = 0; r < 128; ++r) {
    float v = Y[(r0 + r) * 128 + col];
    s += v; q += v * v;
  }
  __shared__ float ss[256], qq[256];
  ss[tid] = s; qq[tid] = q;
  __syncthreads();
  if (tid < 128) {
    atomicAdd(&sum[col], ss[tid] + ss[tid + 128]);
    atomicAdd(&sumsq[col], qq[tid] + qq[tid + 128]);
  }
}

__global__ void bn_finalize(const float* __restrict__ sum, const float* __restrict__ sumsq,
                            const float* __restrict__ g, const float* __restrict__ be,
                            float* __restrict__ scale, float* __restrict__ shift, int N) {
  int j = threadIdx.x;
  float mu = sum[j] / (float)N;
  float var = sumsq[j] / (float)N - mu * mu;
  float a = g[j] * rsqrtf(var + BN_EPS);
  scale[j] = a;
  shift[j] = be[j] - mu * a;
}

// ---------------------------------------------------------------------------
// Apply BN affine + mask-zero; optional per-row infset = (rowsum>0 ? 0 : 1).
// grid = N/2, block 256 (2 rows per block). In-place safe (elementwise).
// ---------------------------------------------------------------------------
__global__ __launch_bounds__(256) void bn_apply(const float* __restrict__ Y,
                                                float* __restrict__ X,
                                                const float* __restrict__ scale,
                                                const float* __restrict__ shift,
                                                const int* __restrict__ mask,
                                                float* __restrict__ infset) {
  const int tid = threadIdx.x;
  const int r = blockIdx.x * 2 + (tid >> 7);
  const int j = tid & 127;
  float v = Y[(long)r * 128 + j] * scale[j] + shift[j];
  if (mask[r] != 0) v = 0.f;
  X[(long)r * 128 + j] = v;
  __shared__ float red[256];
  red[tid] = v;
  __syncthreads();
  for (int s = 64; s > 0; s >>= 1) {
    if ((tid & 127) < s) red[tid] += red[tid + s];
    __syncthreads();
  }
  if (infset != nullptr && (tid & 127) == 0) {
    // sign(mean)>0 -> 0.0 else 1.0 ; mean = sum/128 (exact pow2) so test sum.
    infset[r] = (red[tid] > 0.f) ? 0.f : 1.f;
  }
}

// ---------------------------------------------------------------------------
// Segment-sum head: block g sums xcat rows with idx==g (idx sorted), dots W4,
// writes out[g] = relu(. + b4). block = 384 threads (one per xcat column).
// ---------------------------------------------------------------------------
__global__ __launch_bounds__(384) void seg_out(const float* __restrict__ x_in,
                                               const float* __restrict__ x1,
                                               const float* __restrict__ x2,
                                               const int* __restrict__ idx,
                                               const float* __restrict__ W4,
                                               const float* __restrict__ b4,
                                               float* __restrict__ out, int N) {
  const int g = blockIdx.x, tid = threadIdx.x;
  int lo, hi;
  { int l = 0, h = N; while (l < h) { int m = (l + h) >> 1; if (idx[m] < g) l = m + 1; else h = m; } lo = l; }
  { int l = lo, h = N; while (l < h) { int m = (l + h) >> 1; if (idx[m] < g + 1) l = m + 1; else h = m; } hi = l; }
  const float* src; int c;
  if (tid < 128)      { src = x_in; c = tid; }
  else if (tid < 256) { src = x1;   c = tid - 128; }
  else                { src = x2;   c = tid - 256; }
  float acc = 0.f;
  for (int r = lo; r < hi; ++r) acc += src[(long)r * 128 + c];
  float p = acc * W4[tid];
  __shared__ float red[512];
  red[tid] = p;
  if (tid < 128) red[384 + tid] = 0.f;
  __syncthreads();
  for (int s = 256; s > 0; s >>= 1) {
    if (tid < s) red[tid] += red[tid + s];
    __syncthreads();
  }
  if (tid == 0) out[g] = fmaxf(red[0] + b4[0], 0.f);
}

// ---------------------------------------------------------------------------
// ovr = pos @ infset ; mask seed rows ; global argmax via u64 atomicMax.
// ovr >= 0 always (pos in [0,1), infset in {0,1}) so float-bit packing is
// monotone. Low 32 bits = ~row so ties pick the SMALLEST row (np.argmax).
// ---------------------------------------------------------------------------
__global__ __launch_bounds__(256) void posmv_argmax(const float* __restrict__ pos,
                                                    const float* __restrict__ infset,
                                                    const int* __restrict__ seeds, int n_seeds,
                                                    unsigned long long* __restrict__ slot, int N) {
  const int row = blockIdx.x;
  const int tid = threadIdx.x;
  const float4* p4 = (const float4*)(pos + (long)row * N);
  const float4* s4 = (const float4*)infset;
  float acc = 0.f;
  for (int i = tid; i < N / 4; i += 256) {
    float4 p = p4[i];
    float4 s = s4[i];
    acc += p.x * s.x + p.y * s.y + p.z * s.z + p.w * s.w;
  }
  __shared__ float red[256];
  red[tid] = acc;
  __syncthreads();
  for (int s = 128; s > 0; s >>= 1) {
    if (tid < s) red[tid] += red[tid + s];
    __syncthreads();
  }
  if (tid == 0) {
    bool is_seed = false;
    for (int s = 0; s < n_seeds; ++s) is_seed |= (seeds[s] == row);
    if (!is_seed) {
      unsigned long long key = ((unsigned long long)__float_as_uint(red[0]) << 32) |
                               (unsigned long long)(0xFFFFFFFFu - (unsigned)row);
      atomicMax(slot, key);
    }
  }
}

__global__ void write_seed(const unsigned long long* __restrict__ slot,
                           float* __restrict__ out) {
  unsigned long long v = *slot;
  out[0] = (float)(0xFFFFFFFFu - (unsigned)(v & 0xFFFFFFFFull));
}

// ---------------------------------------------------------------------------
// Launch
// ---------------------------------------------------------------------------
extern "C" void kernel_launch(void* const* d_in, const int* in_sizes, int n_in,
                              void* d_out, int out_size, void* d_ws, size_t ws_size,
                              hipStream_t stream) {
  const int N = NN;
  const float* adj   = (const float*)d_in[0];
  const float* x_in  = (const float*)d_in[1];
  const int*   mask  = (const int*)d_in[2];
  const float* pos   = (const float*)d_in[3];
  const int*   idx   = (const int*)d_in[4];
  const int*   seeds = (const int*)d_in[5];
  // d_in[6] = step (unused)
  const float* W1  = (const float*)d_in[7];
  const float* b1  = (const float*)d_in[8];
  const float* W2  = (const float*)d_in[9];
  const float* b2  = (const float*)d_in[10];
  const float* W4  = (const float*)d_in[11];
  const float* b4  = (const float*)d_in[12];
  const float* g1  = (const float*)d_in[13];
  const float* be1 = (const float*)d_in[14];
  const float* g2  = (const float*)d_in[15];
  const float* be2 = (const float*)d_in[16];

  float* out      = (float*)d_out;        // [0,64)   : relu(h_g@W4+b4)
  float* infset   = out + GG;             // [64,64+N): infset
  float* seed_out = out + GG + N;         // [64+N]   : new_seed

  const size_t mat_bytes = (size_t)N * 128 * sizeof(float);
  char* base = (char*)d_ws;
  float* ax = (float*)base;                       // adj@x (reused for adj@x1)
  float* y1 = (float*)(base + mat_bytes);         // layer1 pre-BN, then x1 in-place
  float* y2 = (float*)(base + 2 * mat_bytes);     // layer2 pre-BN, then x2 in-place
  float* stats = (float*)(base + 3 * mat_bytes);  // 1024 floats + u64 slot
  // stats layout: sum1 sumsq1 scale1 shift1 sum2 sumsq2 scale2 shift2 (128 each)
  unsigned long long* slot = (unsigned long long*)(stats + 1024);

  hipMemsetAsync(stats, 0, 1024 * sizeof(float) + sizeof(unsigned long long), stream);
  hipMemsetAsync(ax, 0, mat_bytes, stream);

  // Layer 1
  gemm_big<<<dim3(N / 64, 2), 256, 0, stream>>>(adj, x_in, ax, N);
  fc_relu<<<N / 64, 256, 0, stream>>>(x_in, ax, W1, b1, y1, N);
  col_stats<<<64, 256, 0, stream>>>(y1, stats + 0, stats + 128);
  bn_finalize<<<1, 128, 0, stream>>>(stats + 0, stats + 128, g1, be1,
                                     stats + 256, stats + 384, N);
  bn_apply<<<N / 2, 256, 0, stream>>>(y1, y1, stats + 256, stats + 384, mask, infset);

  // Layer 2
  hipMemsetAsync(ax, 0, mat_bytes, stream);
  gemm_big<<<dim3(N / 64, 2), 256, 0, stream>>>(adj, y1, ax, N);
  fc_relu<<<N / 64, 256, 0, stream>>>(y1, ax, W2, b2, y2, N);
  col_stats<<<64, 256, 0, stream>>>(y2, stats + 512, stats + 640);
  bn_finalize<<<1, 128, 0, stream>>>(stats + 512, stats + 640, g2, be2,
                                     stats + 768, stats + 896, N);
  bn_apply<<<N / 2, 256, 0, stream>>>(y2, y2, stats + 768, stats + 896, mask, nullptr);

  // Head: segment-sum + W4 + relu
  seg_out<<<GG, 384, 0, stream>>>(x_in, y1, y2, idx, W4, b4, out, N);

  // Influence spread + argmax
  posmv_argmax<<<N, 256, 0, stream>>>(pos, infset, seeds, in_sizes[5], slot, N);
  write_seed<<<1, 1, 0, stream>>>(slot, seed_out);
}